// Round 4
// baseline (302.700 us; speedup 1.0000x reference)
//
#include <hip/hip_runtime.h>
#include <hip/hip_bf16.h>
#include <math.h>

typedef short short8 __attribute__((ext_vector_type(8)));
typedef float f32x4 __attribute__((ext_vector_type(4)));
typedef int i32x4 __attribute__((ext_vector_type(4)));

#define NN 8192
#define FIN 256
#define FOUT 128
#define LRELU_A 0.2f
#define L2E 1.44269504088896f

__device__ __forceinline__ short f2bf(float x) {
    unsigned u = __builtin_bit_cast(unsigned, x);
    unsigned r = (u + 0x7FFFu + ((u >> 16) & 1u)) >> 16;   // RNE
    return (short)r;
}

// K0: pack adj (int32, 256 MB) -> bitmask (8 MB). Pure streaming, BW-bound.
// One block per row; thread t owns cols [32t, 32t+32) -> one u32 word.
__global__ __launch_bounds__(256) void k_pack(const int* __restrict__ adj,
                                              unsigned* __restrict__ packed) {
    const int row = blockIdx.x;
    const int t = threadIdx.x;
    const int* p = adj + (size_t)row * NN + t * 32;
    unsigned m = 0;
    #pragma unroll
    for (int q = 0; q < 8; ++q) {
        i32x4 v = __builtin_nontemporal_load((const i32x4*)(p + q * 4));
        m |= (v.x != 0 ? 1u : 0u) << (q * 4 + 0);
        m |= (v.y != 0 ? 1u : 0u) << (q * 4 + 1);
        m |= (v.z != 0 ? 1u : 0u) << (q * 4 + 2);
        m |= (v.w != 0 ? 1u : 0u) << (q * 4 + 3);
    }
    packed[(size_t)row * (NN / 32) + t] = m;
}

// K1: Wh = h @ W (fp32), fused f1 = Wh@a1, f2 = Wh@a2.
__global__ __launch_bounds__(256) void k_wh(const float* __restrict__ h,
                                            const float* __restrict__ W,
                                            const float* __restrict__ a,
                                            float* __restrict__ Wh,
                                            float* __restrict__ f1,
                                            float* __restrict__ f2) {
    __shared__ float hs[8][FIN];
    const int tid = threadIdx.x;
    const int r0 = blockIdx.x * 8;
    #pragma unroll
    for (int i = 0; i < 2; ++i) {
        int f4 = tid + 256 * i;              // 512 float4 total
        int row = f4 >> 6;
        int k4 = (f4 & 63) << 2;
        *(float4*)&hs[row][k4] = *(const float4*)(h + (size_t)(r0 + row) * FIN + k4);
    }
    __syncthreads();
    const int c4 = (tid & 31) * 4;
    const int row = tid >> 5;
    float acc0 = 0.f, acc1 = 0.f, acc2 = 0.f, acc3 = 0.f;
    #pragma unroll 4
    for (int k = 0; k < FIN; ++k) {
        float hv = hs[row][k];
        float4 w4 = *(const float4*)(W + (size_t)k * FOUT + c4);
        acc0 = fmaf(hv, w4.x, acc0);
        acc1 = fmaf(hv, w4.y, acc1);
        acc2 = fmaf(hv, w4.z, acc2);
        acc3 = fmaf(hv, w4.w, acc3);
    }
    float4 o; o.x = acc0; o.y = acc1; o.z = acc2; o.w = acc3;
    *(float4*)(Wh + (size_t)(r0 + row) * FOUT + c4) = o;

    float4 a1v = *(const float4*)(a + c4);
    float4 a2v = *(const float4*)(a + FOUT + c4);
    float p1 = acc0 * a1v.x + acc1 * a1v.y + acc2 * a1v.z + acc3 * a1v.w;
    float p2 = acc0 * a2v.x + acc1 * a2v.y + acc2 * a2v.z + acc3 * a2v.w;
    #pragma unroll
    for (int m = 1; m <= 16; m <<= 1) {
        p1 += __shfl_xor(p1, m, 64);
        p2 += __shfl_xor(p2, m, 64);
    }
    if ((tid & 31) == 0) {
        f1[r0 + row] = p1;
        f2[r0 + row] = p2;
    }
}

// K1t: WhT[c][r] = bf16(Wh[r][c]) via 32x32 LDS tiles.
__global__ __launch_bounds__(256) void k_transpose(const float* __restrict__ Wh,
                                                   short* __restrict__ WhT) {
    __shared__ float t32[32][33];
    const int tid = threadIdx.x;
    const int tx = tid & 31, ty = tid >> 5;
    const int rb = (blockIdx.x & 255) * 32;
    const int cb = (blockIdx.x >> 8) * 32;
    #pragma unroll
    for (int q = 0; q < 4; ++q) {
        int r = ty + q * 8;
        t32[r][tx] = Wh[(size_t)(rb + r) * FOUT + cb + tx];
    }
    __syncthreads();
    #pragma unroll
    for (int q = 0; q < 4; ++q) {
        int c = ty + q * 8;
        WhT[(size_t)(cb + c) * NN + rb + tx] = f2bf(t32[tx][c]);
    }
}

// K1c: gmax = max(f2)
__global__ __launch_bounds__(256) void k_gmax(const float* __restrict__ f2,
                                              float* __restrict__ gmax) {
    const int tid = threadIdx.x;
    float m = -1e30f;
    for (int i = tid; i < NN; i += 256) m = fmaxf(m, f2[i]);
    #pragma unroll
    for (int s = 1; s <= 32; s <<= 1) m = fmaxf(m, __shfl_xor(m, s, 64));
    __shared__ float red[4];
    if ((tid & 63) == 0) red[tid >> 6] = m;
    __syncthreads();
    if (tid == 0) gmax[0] = fmaxf(fmaxf(red[0], red[1]), fmaxf(red[2], red[3]));
}

// K2: fused mask + leaky_relu + exp + (P @ Wh) via mfma_f32_16x16x32_bf16.
// Mask comes from the 8 MB packed bitmask (L2/L3-resident); all hot-loop
// loads are L2-class. Unroll-2 with named register sets; one-body-ahead
// prefetch of mask/f2; B-fragments loaded at body start.
__global__ __launch_bounds__(256, 4) void k_attn(const unsigned* __restrict__ packed,
                                                 const short* __restrict__ WhT,
                                                 const float* __restrict__ f1,
                                                 const float* __restrict__ f2,
                                                 const float* __restrict__ gmax,
                                                 float* __restrict__ numb,
                                                 float* __restrict__ denb,
                                                 int kchunk, int nsplit) {
    const int tid = threadIdx.x;
    const int lane = tid & 63;
    const int wave = tid >> 6;
    const int split = blockIdx.x & (nsplit - 1);
    const int rt = blockIdx.x / nsplit;
    const int rowbase = rt * 64 + wave * 16;
    const int arow = rowbase + (lane & 15);
    const int kg = lane >> 4;

    const float f1r = f1[arow];
    const float gm = gmax[0];
    const float t0 = f1r + gm;
    const float mhat = fmaxf(t0, LRELU_A * t0);     // row max upper bound
    const float mh2 = mhat * L2E;

    const int kbase0 = split * kchunk;              // 32-aligned
    const int kbase = kbase0 + kg * 8;
    const float* f2p = f2 + kbase;
    const short* wb = WhT + (size_t)(lane & 15) * NN + kbase;
    const unsigned* pkrow = packed + (size_t)arow * (NN / 32) + (kbase0 >> 5);
    const int mshift = kg * 8;

    f32x4 acc[8] = {};
    float den = 0.0f;

    // prologue: A-set holds mask/f2 for koff = 0
    unsigned mwA = pkrow[0];
    float4 faA = *(const float4*)(f2p);
    float4 fbA = *(const float4*)(f2p + 4);

    for (int koff = 0; koff < kchunk; koff += 64) {
        // prefetch B-set (mask/f2 for koff+32)
        unsigned mwB = pkrow[(koff >> 5) + 1];
        float4 faB = *(const float4*)(f2p + koff + 32);
        float4 fbB = *(const float4*)(f2p + koff + 36);

        // ---- body A: koff ----
        {
            short8 b0 = *(const short8*)(wb + (size_t)(0 * 16) * NN + koff);
            short8 b1 = *(const short8*)(wb + (size_t)(1 * 16) * NN + koff);
            short8 b2 = *(const short8*)(wb + (size_t)(2 * 16) * NN + koff);
            short8 b3 = *(const short8*)(wb + (size_t)(3 * 16) * NN + koff);
            short8 b4 = *(const short8*)(wb + (size_t)(4 * 16) * NN + koff);
            short8 b5 = *(const short8*)(wb + (size_t)(5 * 16) * NN + koff);
            short8 b6 = *(const short8*)(wb + (size_t)(6 * 16) * NN + koff);
            short8 b7 = *(const short8*)(wb + (size_t)(7 * 16) * NN + koff);

            const unsigned m8 = (mwA >> mshift) & 0xffu;
            float fv[8] = {faA.x, faA.y, faA.z, faA.w, fbA.x, fbA.y, fbA.z, fbA.w};
            short8 af;
            #pragma unroll
            for (int i = 0; i < 8; ++i) {
                float e = f1r + fv[i];
                e = fmaxf(e, LRELU_A * e);
                float p = __builtin_amdgcn_exp2f(fmaf(e, L2E, -mh2));
                p = (m8 & (1u << i)) ? p : 0.0f;
                den += p;
                af[i] = f2bf(p);
            }

            // prefetch A-set for koff+64 (guarded, uniform select)
            {
                const int kn = (koff + 64 < kchunk) ? koff + 64 : 0;
                mwA = pkrow[kn >> 5];
                faA = *(const float4*)(f2p + kn);
                fbA = *(const float4*)(f2p + kn + 4);
            }

            acc[0] = __builtin_amdgcn_mfma_f32_16x16x32_bf16(af, b0, acc[0], 0, 0, 0);
            acc[1] = __builtin_amdgcn_mfma_f32_16x16x32_bf16(af, b1, acc[1], 0, 0, 0);
            acc[2] = __builtin_amdgcn_mfma_f32_16x16x32_bf16(af, b2, acc[2], 0, 0, 0);
            acc[3] = __builtin_amdgcn_mfma_f32_16x16x32_bf16(af, b3, acc[3], 0, 0, 0);
            acc[4] = __builtin_amdgcn_mfma_f32_16x16x32_bf16(af, b4, acc[4], 0, 0, 0);
            acc[5] = __builtin_amdgcn_mfma_f32_16x16x32_bf16(af, b5, acc[5], 0, 0, 0);
            acc[6] = __builtin_amdgcn_mfma_f32_16x16x32_bf16(af, b6, acc[6], 0, 0, 0);
            acc[7] = __builtin_amdgcn_mfma_f32_16x16x32_bf16(af, b7, acc[7], 0, 0, 0);
        }

        // ---- body B: koff+32 ----
        {
            const int kb = koff + 32;
            short8 b0 = *(const short8*)(wb + (size_t)(0 * 16) * NN + kb);
            short8 b1 = *(const short8*)(wb + (size_t)(1 * 16) * NN + kb);
            short8 b2 = *(const short8*)(wb + (size_t)(2 * 16) * NN + kb);
            short8 b3 = *(const short8*)(wb + (size_t)(3 * 16) * NN + kb);
            short8 b4 = *(const short8*)(wb + (size_t)(4 * 16) * NN + kb);
            short8 b5 = *(const short8*)(wb + (size_t)(5 * 16) * NN + kb);
            short8 b6 = *(const short8*)(wb + (size_t)(6 * 16) * NN + kb);
            short8 b7 = *(const short8*)(wb + (size_t)(7 * 16) * NN + kb);

            const unsigned m8 = (mwB >> mshift) & 0xffu;
            float fv[8] = {faB.x, faB.y, faB.z, faB.w, fbB.x, fbB.y, fbB.z, fbB.w};
            short8 af;
            #pragma unroll
            for (int i = 0; i < 8; ++i) {
                float e = f1r + fv[i];
                e = fmaxf(e, LRELU_A * e);
                float p = __builtin_amdgcn_exp2f(fmaf(e, L2E, -mh2));
                p = (m8 & (1u << i)) ? p : 0.0f;
                den += p;
                af[i] = f2bf(p);
            }

            acc[0] = __builtin_amdgcn_mfma_f32_16x16x32_bf16(af, b0, acc[0], 0, 0, 0);
            acc[1] = __builtin_amdgcn_mfma_f32_16x16x32_bf16(af, b1, acc[1], 0, 0, 0);
            acc[2] = __builtin_amdgcn_mfma_f32_16x16x32_bf16(af, b2, acc[2], 0, 0, 0);
            acc[3] = __builtin_amdgcn_mfma_f32_16x16x32_bf16(af, b3, acc[3], 0, 0, 0);
            acc[4] = __builtin_amdgcn_mfma_f32_16x16x32_bf16(af, b4, acc[4], 0, 0, 0);
            acc[5] = __builtin_amdgcn_mfma_f32_16x16x32_bf16(af, b5, acc[5], 0, 0, 0);
            acc[6] = __builtin_amdgcn_mfma_f32_16x16x32_bf16(af, b6, acc[6], 0, 0, 0);
            acc[7] = __builtin_amdgcn_mfma_f32_16x16x32_bf16(af, b7, acc[7], 0, 0, 0);
        }
    }

    // reduce den across the 4 k-groups
    den += __shfl_xor(den, 16, 64);
    den += __shfl_xor(den, 32, 64);
    if (lane < 16) denb[(size_t)split * NN + rowbase + lane] = den;

    float* np = numb + ((size_t)split * NN + rowbase) * FOUT;
    const int col = lane & 15;
    const int rsub = (lane >> 4) * 4;
    #pragma unroll
    for (int t = 0; t < 8; ++t) {
        #pragma unroll
        for (int r = 0; r < 4; ++r) {
            np[(size_t)(rsub + r) * FOUT + t * 16 + col] = acc[t][r];
        }
    }
}

// K3: sum split partials, divide, ELU.
__global__ __launch_bounds__(256) void k_final(const float* __restrict__ numb,
                                               const float* __restrict__ denb,
                                               float* __restrict__ out,
                                               int splitk) {
    const int idx = blockIdx.x * 256 + threadIdx.x;
    const int row = idx >> 7;
    float s = 0.0f, d = 0.0f;
    for (int sp = 0; sp < splitk; ++sp) {
        s += numb[((size_t)sp * NN) * FOUT + idx];
        d += denb[(size_t)sp * NN + row];
    }
    float v = s / d;
    out[idx] = v > 0.0f ? v : expm1f(v);
}

extern "C" void kernel_launch(void* const* d_in, const int* in_sizes, int n_in,
                              void* d_out, int out_size, void* d_ws, size_t ws_size,
                              hipStream_t stream) {
    const float* h = (const float*)d_in[0];
    const int* adj = (const int*)d_in[1];
    const float* W = (const float*)d_in[2];
    const float* a = (const float*)d_in[3];
    float* out = (float*)d_out;

    char* ws = (char*)d_ws;
    size_t off = 0;
    auto alloc = [&](size_t nbytes) {
        char* p = ws + off;
        off = (off + nbytes + 255) & ~(size_t)255;
        return p;
    };
    float* Wh      = (float*)alloc((size_t)NN * FOUT * 4);
    short* WhT     = (short*)alloc((size_t)FOUT * NN * 2);
    float* f1      = (float*)alloc(NN * 4);
    float* f2      = (float*)alloc(NN * 4);
    float* gmx     = (float*)alloc(256);
    unsigned* pkd  = (unsigned*)alloc((size_t)NN * (NN / 32) * 4);   // 8 MB

    int splitk = 8;
    while (splitk > 1 &&
           off + (size_t)splitk * ((size_t)NN * FOUT * 4 + NN * 4 + 512) > ws_size)
        splitk >>= 1;
    float* numb = (float*)alloc((size_t)splitk * NN * FOUT * 4);
    float* denb = (float*)alloc((size_t)splitk * NN * 4);
    const int kchunk = NN / splitk;

    k_pack<<<NN, 256, 0, stream>>>(adj, pkd);
    k_wh<<<NN / 8, 256, 0, stream>>>(h, W, a, Wh, f1, f2);
    k_transpose<<<(NN / 32) * (FOUT / 32), 256, 0, stream>>>(Wh, WhT);
    k_gmax<<<1, 256, 0, stream>>>(f2, gmx);
    k_attn<<<(NN / 64) * splitk, 256, 0, stream>>>(pkd, WhT, f1, f2, gmx, numb, denb,
                                                   kchunk, splitk);
    k_final<<<NN * FOUT / 256, 256, 0, stream>>>(numb, denb, out, splitk);
}

// Round 5
// 204.240 us; speedup vs baseline: 1.4821x; 1.4821x over previous
//
#include <hip/hip_runtime.h>
#include <hip/hip_bf16.h>
#include <math.h>

typedef short short8 __attribute__((ext_vector_type(8)));
typedef float f32x4 __attribute__((ext_vector_type(4)));
typedef int i32x4 __attribute__((ext_vector_type(4)));

#define NN 8192
#define FIN 256
#define FOUT 128
#define LRELU_A 0.2f
#define L2E 1.44269504088896f

__device__ __forceinline__ short f2bf(float x) {
    unsigned u = __builtin_bit_cast(unsigned, x);
    unsigned r = (u + 0x7FFFu + ((u >> 16) & 1u)) >> 16;   // RNE
    return (short)r;
}

// K0: pack adj (int32, 256 MB) -> bitmask (8 MB). Pure streaming, BW-bound.
__global__ __launch_bounds__(256) void k_pack(const int* __restrict__ adj,
                                              unsigned* __restrict__ packed) {
    const int row = blockIdx.x;
    const int t = threadIdx.x;
    const int* p = adj + (size_t)row * NN + t * 32;
    unsigned m = 0;
    #pragma unroll
    for (int q = 0; q < 8; ++q) {
        i32x4 v = __builtin_nontemporal_load((const i32x4*)(p + q * 4));
        m |= (v.x != 0 ? 1u : 0u) << (q * 4 + 0);
        m |= (v.y != 0 ? 1u : 0u) << (q * 4 + 1);
        m |= (v.z != 0 ? 1u : 0u) << (q * 4 + 2);
        m |= (v.w != 0 ? 1u : 0u) << (q * 4 + 3);
    }
    packed[(size_t)row * (NN / 32) + t] = m;
}

// K1: Wh = h @ W (fp32), fused f1 = Wh@a1, f2 = Wh@a2.
__global__ __launch_bounds__(256) void k_wh(const float* __restrict__ h,
                                            const float* __restrict__ W,
                                            const float* __restrict__ a,
                                            float* __restrict__ Wh,
                                            float* __restrict__ f1,
                                            float* __restrict__ f2) {
    __shared__ float hs[8][FIN];
    const int tid = threadIdx.x;
    const int r0 = blockIdx.x * 8;
    #pragma unroll
    for (int i = 0; i < 2; ++i) {
        int f4 = tid + 256 * i;              // 512 float4 total
        int row = f4 >> 6;
        int k4 = (f4 & 63) << 2;
        *(float4*)&hs[row][k4] = *(const float4*)(h + (size_t)(r0 + row) * FIN + k4);
    }
    __syncthreads();
    const int c4 = (tid & 31) * 4;
    const int row = tid >> 5;
    float acc0 = 0.f, acc1 = 0.f, acc2 = 0.f, acc3 = 0.f;
    #pragma unroll 4
    for (int k = 0; k < FIN; ++k) {
        float hv = hs[row][k];
        float4 w4 = *(const float4*)(W + (size_t)k * FOUT + c4);
        acc0 = fmaf(hv, w4.x, acc0);
        acc1 = fmaf(hv, w4.y, acc1);
        acc2 = fmaf(hv, w4.z, acc2);
        acc3 = fmaf(hv, w4.w, acc3);
    }
    float4 o; o.x = acc0; o.y = acc1; o.z = acc2; o.w = acc3;
    *(float4*)(Wh + (size_t)(r0 + row) * FOUT + c4) = o;

    float4 a1v = *(const float4*)(a + c4);
    float4 a2v = *(const float4*)(a + FOUT + c4);
    float p1 = acc0 * a1v.x + acc1 * a1v.y + acc2 * a1v.z + acc3 * a1v.w;
    float p2 = acc0 * a2v.x + acc1 * a2v.y + acc2 * a2v.z + acc3 * a2v.w;
    #pragma unroll
    for (int m = 1; m <= 16; m <<= 1) {
        p1 += __shfl_xor(p1, m, 64);
        p2 += __shfl_xor(p2, m, 64);
    }
    if ((tid & 31) == 0) {
        f1[r0 + row] = p1;
        f2[r0 + row] = p2;
    }
}

// K1t: WhT[c][r] = bf16(Wh[r][c]) via 32x32 LDS tiles.
__global__ __launch_bounds__(256) void k_transpose(const float* __restrict__ Wh,
                                                   short* __restrict__ WhT) {
    __shared__ float t32[32][33];
    const int tid = threadIdx.x;
    const int tx = tid & 31, ty = tid >> 5;
    const int rb = (blockIdx.x & 255) * 32;
    const int cb = (blockIdx.x >> 8) * 32;
    #pragma unroll
    for (int q = 0; q < 4; ++q) {
        int r = ty + q * 8;
        t32[r][tx] = Wh[(size_t)(rb + r) * FOUT + cb + tx];
    }
    __syncthreads();
    #pragma unroll
    for (int q = 0; q < 4; ++q) {
        int c = ty + q * 8;
        WhT[(size_t)(cb + c) * NN + rb + tx] = f2bf(t32[tx][c]);
    }
}

// K1c: gmax = max(f2)
__global__ __launch_bounds__(256) void k_gmax(const float* __restrict__ f2,
                                              float* __restrict__ gmax) {
    const int tid = threadIdx.x;
    float m = -1e30f;
    for (int i = tid; i < NN; i += 256) m = fmaxf(m, f2[i]);
    #pragma unroll
    for (int s = 1; s <= 32; s <<= 1) m = fmaxf(m, __shfl_xor(m, s, 64));
    __shared__ float red[4];
    if ((tid & 63) == 0) red[tid >> 6] = m;
    __syncthreads();
    if (tid == 0) gmax[0] = fmaxf(fmaxf(red[0], red[1]), fmaxf(red[2], red[3]));
}

// K2: fused mask + leaky_relu + exp + (P @ Wh) via mfma_f32_16x16x32_bf16.
// WhT tile (128 rows x 64 cols bf16 = 16 KB) staged in LDS per 64-col step,
// XOR-swizzled (slot ^= n&7) so ds_read_b128 B-fragment reads are
// conflict-free. Reg-staged: global loads issued before compute, ds_write
// after barrier (T14). 2 barriers/step, single LDS buffer.
__global__ __launch_bounds__(256, 4) void k_attn(const unsigned* __restrict__ packed,
                                                 const short* __restrict__ WhT,
                                                 const float* __restrict__ f1,
                                                 const float* __restrict__ f2,
                                                 const float* __restrict__ gmax,
                                                 float* __restrict__ numb,
                                                 float* __restrict__ denb,
                                                 int kchunk, int nsplit) {
    __shared__ __align__(16) short ldsW[8192];   // [128 rows][64 cols], swizzled
    const int tid = threadIdx.x;
    const int lane = tid & 63;
    const int wave = tid >> 6;
    const int split = blockIdx.x & (nsplit - 1);
    const int rt = blockIdx.x / nsplit;
    const int rowbase = rt * 64 + wave * 16;
    const int col = lane & 15;
    const int kg = lane >> 4;
    const int arow = rowbase + col;

    const float f1r = f1[arow];
    const float gm = gmax[0];
    const float t0 = f1r + gm;
    const float mhat = fmaxf(t0, LRELU_A * t0);     // row max upper bound
    const float mh2 = mhat * L2E;

    const int kbase0 = split * kchunk;              // multiple of 1024
    const float* f2p = f2 + kbase0 + kg * 8;
    const unsigned* pkrow = packed + (size_t)arow * (NN / 32) + (kbase0 >> 5);

    // staging map: thread stages rows n = (tid>>3) + 32q, global j-slot ts=tid&7,
    // LDS slot = ts ^ (n&7)  (n&7 == (tid>>3)&7 since 32q = 0 mod 8)
    const int tq = tid >> 3;                        // 0..31
    const int ts = tid & 7;
    const short* wsrc = WhT + (size_t)tq * NN + kbase0 + ts * 8;
    short* wdst = &ldsW[tq * 64 + ((ts ^ (tq & 7)) * 8)];

    // compute-read map: row n = t*16+col (n&7 == col&7), slot = (b*4+kg)^(n&7)
    const short* lrd0 = &ldsW[col * 64 + ((kg ^ (col & 7)) * 8)];           // body 0
    const short* lrd1 = (const short*)((const char*)lrd0) + 0;              // placeholder
    lrd1 = lrd0 + 32;                       // wrong in general; fixed below via XOR
    // (slot^4)*8 shorts = base XOR 32 shorts when slot<4 toggles bit2 -> ^32 shorts
    lrd1 = (const short*)&ldsW[(col * 64) + (((kg ^ (col & 7)) * 8) ^ 32)];

    f32x4 acc[8] = {};
    float den = 0.0f;
    const int nsteps = kchunk / 64;

    // prologue: stage tile 0
    {
        short8 r0 = *(const short8*)(wsrc);
        short8 r1 = *(const short8*)(wsrc + 32 * NN);
        short8 r2 = *(const short8*)(wsrc + 64 * NN);
        short8 r3 = *(const short8*)(wsrc + 96 * NN);
        *(short8*)(wdst) = r0;
        *(short8*)(wdst + 2048) = r1;
        *(short8*)(wdst + 4096) = r2;
        *(short8*)(wdst + 6144) = r3;
    }
    __syncthreads();

    for (int step = 0; step < nsteps; ++step) {
        const int koff = step * 64;
        const int kn = (step + 1 < nsteps) ? koff + 64 : 0;

        // issue next-tile global loads early (latency hides under compute)
        short8 r0, r1, r2, r3;
        {
            const short* ws = wsrc + kn;
            r0 = *(const short8*)(ws);
            r1 = *(const short8*)(ws + 32 * NN);
            r2 = *(const short8*)(ws + 64 * NN);
            r3 = *(const short8*)(ws + 96 * NN);
        }

        // current-step mask + f2
        uint2 mw = *(const uint2*)(pkrow + (koff >> 5));
        float4 fa0 = *(const float4*)(f2p + koff);
        float4 fb0 = *(const float4*)(f2p + koff + 4);
        float4 fa1 = *(const float4*)(f2p + koff + 32);
        float4 fb1 = *(const float4*)(f2p + koff + 36);

        // ---- body 0 (cols koff..koff+31) ----
        {
            short8 b0 = *(const short8*)(lrd0 + 0 * 1024);
            short8 b1 = *(const short8*)(lrd0 + 1 * 1024);
            short8 b2 = *(const short8*)(lrd0 + 2 * 1024);
            short8 b3 = *(const short8*)(lrd0 + 3 * 1024);
            short8 b4 = *(const short8*)(lrd0 + 4 * 1024);
            short8 b5 = *(const short8*)(lrd0 + 5 * 1024);
            short8 b6 = *(const short8*)(lrd0 + 6 * 1024);
            short8 b7 = *(const short8*)(lrd0 + 7 * 1024);

            const unsigned m8 = (mw.x >> (kg * 8)) & 0xffu;
            float fv[8] = {fa0.x, fa0.y, fa0.z, fa0.w, fb0.x, fb0.y, fb0.z, fb0.w};
            short8 af;
            #pragma unroll
            for (int i = 0; i < 8; ++i) {
                float e = f1r + fv[i];
                e = fmaxf(e, LRELU_A * e);
                float p = __builtin_amdgcn_exp2f(fmaf(e, L2E, -mh2));
                p = (m8 & (1u << i)) ? p : 0.0f;
                den += p;
                af[i] = f2bf(p);
            }
            acc[0] = __builtin_amdgcn_mfma_f32_16x16x32_bf16(af, b0, acc[0], 0, 0, 0);
            acc[1] = __builtin_amdgcn_mfma_f32_16x16x32_bf16(af, b1, acc[1], 0, 0, 0);
            acc[2] = __builtin_amdgcn_mfma_f32_16x16x32_bf16(af, b2, acc[2], 0, 0, 0);
            acc[3] = __builtin_amdgcn_mfma_f32_16x16x32_bf16(af, b3, acc[3], 0, 0, 0);
            acc[4] = __builtin_amdgcn_mfma_f32_16x16x32_bf16(af, b4, acc[4], 0, 0, 0);
            acc[5] = __builtin_amdgcn_mfma_f32_16x16x32_bf16(af, b5, acc[5], 0, 0, 0);
            acc[6] = __builtin_amdgcn_mfma_f32_16x16x32_bf16(af, b6, acc[6], 0, 0, 0);
            acc[7] = __builtin_amdgcn_mfma_f32_16x16x32_bf16(af, b7, acc[7], 0, 0, 0);
        }

        // ---- body 1 (cols koff+32..koff+63) ----
        {
            short8 b0 = *(const short8*)(lrd1 + 0 * 1024);
            short8 b1 = *(const short8*)(lrd1 + 1 * 1024);
            short8 b2 = *(const short8*)(lrd1 + 2 * 1024);
            short8 b3 = *(const short8*)(lrd1 + 3 * 1024);
            short8 b4 = *(const short8*)(lrd1 + 4 * 1024);
            short8 b5 = *(const short8*)(lrd1 + 5 * 1024);
            short8 b6 = *(const short8*)(lrd1 + 6 * 1024);
            short8 b7 = *(const short8*)(lrd1 + 7 * 1024);

            const unsigned m8 = (mw.y >> (kg * 8)) & 0xffu;
            float fv[8] = {fa1.x, fa1.y, fa1.z, fa1.w, fb1.x, fb1.y, fb1.z, fb1.w};
            short8 af;
            #pragma unroll
            for (int i = 0; i < 8; ++i) {
                float e = f1r + fv[i];
                e = fmaxf(e, LRELU_A * e);
                float p = __builtin_amdgcn_exp2f(fmaf(e, L2E, -mh2));
                p = (m8 & (1u << i)) ? p : 0.0f;
                den += p;
                af[i] = f2bf(p);
            }
            acc[0] = __builtin_amdgcn_mfma_f32_16x16x32_bf16(af, b0, acc[0], 0, 0, 0);
            acc[1] = __builtin_amdgcn_mfma_f32_16x16x32_bf16(af, b1, acc[1], 0, 0, 0);
            acc[2] = __builtin_amdgcn_mfma_f32_16x16x32_bf16(af, b2, acc[2], 0, 0, 0);
            acc[3] = __builtin_amdgcn_mfma_f32_16x16x32_bf16(af, b3, acc[3], 0, 0, 0);
            acc[4] = __builtin_amdgcn_mfma_f32_16x16x32_bf16(af, b4, acc[4], 0, 0, 0);
            acc[5] = __builtin_amdgcn_mfma_f32_16x16x32_bf16(af, b5, acc[5], 0, 0, 0);
            acc[6] = __builtin_amdgcn_mfma_f32_16x16x32_bf16(af, b6, acc[6], 0, 0, 0);
            acc[7] = __builtin_amdgcn_mfma_f32_16x16x32_bf16(af, b7, acc[7], 0, 0, 0);
        }

        __syncthreads();                    // all waves done reading ldsW
        *(short8*)(wdst) = r0;              // write next tile
        *(short8*)(wdst + 2048) = r1;
        *(short8*)(wdst + 4096) = r2;
        *(short8*)(wdst + 6144) = r3;
        __syncthreads();                    // next tile visible
    }

    // reduce den across the 4 kg groups
    den += __shfl_xor(den, 16, 64);
    den += __shfl_xor(den, 32, 64);
    if (lane < 16) denb[(size_t)split * NN + rowbase + lane] = den;

    float* np = numb + ((size_t)split * NN + rowbase) * FOUT;
    const int rsub = (lane >> 4) * 4;
    #pragma unroll
    for (int t = 0; t < 8; ++t) {
        #pragma unroll
        for (int r = 0; r < 4; ++r) {
            np[(size_t)(rsub + r) * FOUT + t * 16 + col] = acc[t][r];
        }
    }
}

// K3: sum split partials, divide, ELU.
__global__ __launch_bounds__(256) void k_final(const float* __restrict__ numb,
                                               const float* __restrict__ denb,
                                               float* __restrict__ out,
                                               int splitk) {
    const int idx = blockIdx.x * 256 + threadIdx.x;
    const int row = idx >> 7;
    float s = 0.0f, d = 0.0f;
    for (int sp = 0; sp < splitk; ++sp) {
        s += numb[((size_t)sp * NN) * FOUT + idx];
        d += denb[(size_t)sp * NN + row];
    }
    float v = s / d;
    out[idx] = v > 0.0f ? v : expm1f(v);
}

extern "C" void kernel_launch(void* const* d_in, const int* in_sizes, int n_in,
                              void* d_out, int out_size, void* d_ws, size_t ws_size,
                              hipStream_t stream) {
    const float* h = (const float*)d_in[0];
    const int* adj = (const int*)d_in[1];
    const float* W = (const float*)d_in[2];
    const float* a = (const float*)d_in[3];
    float* out = (float*)d_out;

    char* ws = (char*)d_ws;
    size_t off = 0;
    auto alloc = [&](size_t nbytes) {
        char* p = ws + off;
        off = (off + nbytes + 255) & ~(size_t)255;
        return p;
    };
    float* Wh      = (float*)alloc((size_t)NN * FOUT * 4);
    short* WhT     = (short*)alloc((size_t)FOUT * NN * 2);
    float* f1      = (float*)alloc(NN * 4);
    float* f2      = (float*)alloc(NN * 4);
    float* gmx     = (float*)alloc(256);
    unsigned* pkd  = (unsigned*)alloc((size_t)NN * (NN / 32) * 4);   // 8 MB

    int splitk = 8;
    while (splitk > 1 &&
           off + (size_t)splitk * ((size_t)NN * FOUT * 4 + NN * 4 + 512) > ws_size)
        splitk >>= 1;
    float* numb = (float*)alloc((size_t)splitk * NN * FOUT * 4);
    float* denb = (float*)alloc((size_t)splitk * NN * 4);
    const int kchunk = NN / splitk;

    k_pack<<<NN, 256, 0, stream>>>(adj, pkd);
    k_wh<<<NN / 8, 256, 0, stream>>>(h, W, a, Wh, f1, f2);
    k_transpose<<<(NN / 32) * (FOUT / 32), 256, 0, stream>>>(Wh, WhT);
    k_gmax<<<1, 256, 0, stream>>>(f2, gmx);
    k_attn<<<(NN / 64) * splitk, 256, 0, stream>>>(pkd, WhT, f1, f2, gmx, numb, denb,
                                                   kchunk, splitk);
    k_final<<<NN * FOUT / 256, 256, 0, stream>>>(numb, denb, out, splitk);
}

// Round 6
// 142.027 us; speedup vs baseline: 2.1313x; 1.4380x over previous
//
#include <hip/hip_runtime.h>
#include <hip/hip_bf16.h>
#include <math.h>

typedef short short8 __attribute__((ext_vector_type(8)));
typedef float f32x4 __attribute__((ext_vector_type(4)));
typedef int i32x4 __attribute__((ext_vector_type(4)));

#define NN 8192
#define FIN 256
#define FOUT 128
#define LRELU_A 0.2f
#define L2E 1.44269504088896f

__device__ __forceinline__ short f2bf(float x) {
    unsigned u = __builtin_bit_cast(unsigned, x);
    unsigned r = (u + 0x7FFFu + ((u >> 16) & 1u)) >> 16;   // RNE
    return (short)r;
}

// K1: Wh = h @ W (fp32), fused f1 = Wh@a1, f2 = Wh@a2.
__global__ __launch_bounds__(256) void k_wh(const float* __restrict__ h,
                                            const float* __restrict__ W,
                                            const float* __restrict__ a,
                                            float* __restrict__ Wh,
                                            float* __restrict__ f1,
                                            float* __restrict__ f2) {
    __shared__ float hs[8][FIN];
    const int tid = threadIdx.x;
    const int r0 = blockIdx.x * 8;
    #pragma unroll
    for (int i = 0; i < 2; ++i) {
        int f4 = tid + 256 * i;              // 512 float4 total
        int row = f4 >> 6;
        int k4 = (f4 & 63) << 2;
        *(float4*)&hs[row][k4] = *(const float4*)(h + (size_t)(r0 + row) * FIN + k4);
    }
    __syncthreads();
    const int c4 = (tid & 31) * 4;
    const int row = tid >> 5;
    float acc0 = 0.f, acc1 = 0.f, acc2 = 0.f, acc3 = 0.f;
    #pragma unroll 4
    for (int k = 0; k < FIN; ++k) {
        float hv = hs[row][k];
        float4 w4 = *(const float4*)(W + (size_t)k * FOUT + c4);
        acc0 = fmaf(hv, w4.x, acc0);
        acc1 = fmaf(hv, w4.y, acc1);
        acc2 = fmaf(hv, w4.z, acc2);
        acc3 = fmaf(hv, w4.w, acc3);
    }
    float4 o; o.x = acc0; o.y = acc1; o.z = acc2; o.w = acc3;
    *(float4*)(Wh + (size_t)(r0 + row) * FOUT + c4) = o;

    float4 a1v = *(const float4*)(a + c4);
    float4 a2v = *(const float4*)(a + FOUT + c4);
    float p1 = acc0 * a1v.x + acc1 * a1v.y + acc2 * a1v.z + acc3 * a1v.w;
    float p2 = acc0 * a2v.x + acc1 * a2v.y + acc2 * a2v.z + acc3 * a2v.w;
    #pragma unroll
    for (int m = 1; m <= 16; m <<= 1) {
        p1 += __shfl_xor(p1, m, 64);
        p2 += __shfl_xor(p2, m, 64);
    }
    if ((tid & 31) == 0) {
        f1[r0 + row] = p1;
        f2[r0 + row] = p2;
    }
}

// K1t: WhT[c][r] = bf16(Wh[r][c]) via 32x32 LDS tiles.
__global__ __launch_bounds__(256) void k_transpose(const float* __restrict__ Wh,
                                                   short* __restrict__ WhT) {
    __shared__ float t32[32][33];
    const int tid = threadIdx.x;
    const int tx = tid & 31, ty = tid >> 5;
    const int rb = (blockIdx.x & 255) * 32;
    const int cb = (blockIdx.x >> 8) * 32;
    #pragma unroll
    for (int q = 0; q < 4; ++q) {
        int r = ty + q * 8;
        t32[r][tx] = Wh[(size_t)(rb + r) * FOUT + cb + tx];
    }
    __syncthreads();
    #pragma unroll
    for (int q = 0; q < 4; ++q) {
        int c = ty + q * 8;
        WhT[(size_t)(cb + c) * NN + rb + tx] = f2bf(t32[tx][c]);
    }
}

// K1c: gmax = max(f2)
__global__ __launch_bounds__(256) void k_gmax(const float* __restrict__ f2,
                                              float* __restrict__ gmax) {
    const int tid = threadIdx.x;
    float m = -1e30f;
    for (int i = tid; i < NN; i += 256) m = fmaxf(m, f2[i]);
    #pragma unroll
    for (int s = 1; s <= 32; s <<= 1) m = fmaxf(m, __shfl_xor(m, s, 64));
    __shared__ float red[4];
    if ((tid & 63) == 0) red[tid >> 6] = m;
    __syncthreads();
    if (tid == 0) gmax[0] = fmaxf(fmaxf(red[0], red[1]), fmaxf(red[2], red[3]));
}

__device__ __forceinline__ void gat_body(const short* __restrict__ lrd, unsigned m8,
                                         float4 fa, float4 fb,
                                         float f1r, float mh2, float& den,
                                         f32x4 acc[8]) {
    short8 b0 = *(const short8*)(lrd + 0 * 1024);
    short8 b1 = *(const short8*)(lrd + 1 * 1024);
    short8 b2 = *(const short8*)(lrd + 2 * 1024);
    short8 b3 = *(const short8*)(lrd + 3 * 1024);
    short8 b4 = *(const short8*)(lrd + 4 * 1024);
    short8 b5 = *(const short8*)(lrd + 5 * 1024);
    short8 b6 = *(const short8*)(lrd + 6 * 1024);
    short8 b7 = *(const short8*)(lrd + 7 * 1024);

    float fv[8] = {fa.x, fa.y, fa.z, fa.w, fb.x, fb.y, fb.z, fb.w};
    short8 af;
    #pragma unroll
    for (int i = 0; i < 8; ++i) {
        float e = f1r + fv[i];
        e = fmaxf(e, LRELU_A * e);
        float p = __builtin_amdgcn_exp2f(fmaf(e, L2E, -mh2));
        p = (m8 & (1u << i)) ? p : 0.0f;
        den += p;
        af[i] = f2bf(p);
    }
    acc[0] = __builtin_amdgcn_mfma_f32_16x16x32_bf16(af, b0, acc[0], 0, 0, 0);
    acc[1] = __builtin_amdgcn_mfma_f32_16x16x32_bf16(af, b1, acc[1], 0, 0, 0);
    acc[2] = __builtin_amdgcn_mfma_f32_16x16x32_bf16(af, b2, acc[2], 0, 0, 0);
    acc[3] = __builtin_amdgcn_mfma_f32_16x16x32_bf16(af, b3, acc[3], 0, 0, 0);
    acc[4] = __builtin_amdgcn_mfma_f32_16x16x32_bf16(af, b4, acc[4], 0, 0, 0);
    acc[5] = __builtin_amdgcn_mfma_f32_16x16x32_bf16(af, b5, acc[5], 0, 0, 0);
    acc[6] = __builtin_amdgcn_mfma_f32_16x16x32_bf16(af, b6, acc[6], 0, 0, 0);
    acc[7] = __builtin_amdgcn_mfma_f32_16x16x32_bf16(af, b7, acc[7], 0, 0, 0);
}

// One pipeline step: masks extracted from 2-step-old adj regs, stage loads
// (tile s+1) issued BEFORE adj prefetch (tile s+2) so the compiler's counted
// vmcnt before ds_write does not drain the adj queue. Barrier waits
// lgkmcnt(0) ONLY (global loads stay in flight across it).
#define GAT_STEP(KOFF, X0, X1, X2, X3, LRD0, LRD1, WDST)                           \
    {                                                                              \
        const int koff_ = (KOFF);                                                  \
        float4 fa0 = *(const float4*)(f2p + koff_);                                \
        float4 fb0 = *(const float4*)(f2p + koff_ + 4);                            \
        float4 fa1 = *(const float4*)(f2p + koff_ + 32);                           \
        float4 fb1 = *(const float4*)(f2p + koff_ + 36);                           \
        unsigned m0 = (unsigned)(X0.x & 1)        | ((unsigned)(X0.y & 1) << 1) |  \
                      ((unsigned)(X0.z & 1) << 2) | ((unsigned)(X0.w & 1) << 3) |  \
                      ((unsigned)(X1.x & 1) << 4) | ((unsigned)(X1.y & 1) << 5) |  \
                      ((unsigned)(X1.z & 1) << 6) | ((unsigned)(X1.w & 1) << 7);   \
        unsigned m1 = (unsigned)(X2.x & 1)        | ((unsigned)(X2.y & 1) << 1) |  \
                      ((unsigned)(X2.z & 1) << 2) | ((unsigned)(X2.w & 1) << 3) |  \
                      ((unsigned)(X3.x & 1) << 4) | ((unsigned)(X3.y & 1) << 5) |  \
                      ((unsigned)(X3.z & 1) << 6) | ((unsigned)(X3.w & 1) << 7);   \
        const int kst_ = (koff_ + 64 < kchunk) ? koff_ + 64 : 0;                   \
        short8 r0 = *(const short8*)(wsrc + kst_);                                 \
        short8 r1 = *(const short8*)(wsrc + kst_ + 32 * NN);                       \
        short8 r2 = *(const short8*)(wsrc + kst_ + 64 * NN);                       \
        short8 r3 = *(const short8*)(wsrc + kst_ + 96 * NN);                       \
        const int kpre_ = (koff_ + 128 < kchunk) ? koff_ + 128 : 0;                \
        X0 = *(const i32x4*)(adjp + kpre_);                                        \
        X1 = *(const i32x4*)(adjp + kpre_ + 4);                                    \
        X2 = *(const i32x4*)(adjp + kpre_ + 32);                                   \
        X3 = *(const i32x4*)(adjp + kpre_ + 36);                                   \
        gat_body(LRD0, m0, fa0, fb0, f1r, mh2, den, acc);                          \
        gat_body(LRD1, m1, fa1, fb1, f1r, mh2, den, acc);                          \
        *(short8*)(WDST) = r0;                                                     \
        *(short8*)(WDST + 2048) = r1;                                              \
        *(short8*)(WDST + 4096) = r2;                                              \
        *(short8*)(WDST + 6144) = r3;                                              \
        asm volatile("s_waitcnt lgkmcnt(0)" ::: "memory");                         \
        __builtin_amdgcn_s_barrier();                                              \
    }

// K2: fused mask + leaky_relu + exp + (P @ Wh) via mfma_f32_16x16x32_bf16.
// Raw adj read (the irreducible 256 MB stream) with 2-step-ahead register
// prefetch; WhT staged in double-buffered XOR-swizzled LDS; one lgkm-only
// barrier per 64-col step.
__global__ __launch_bounds__(256, 3) void k_attn(const int* __restrict__ adj,
                                                 const short* __restrict__ WhT,
                                                 const float* __restrict__ f1,
                                                 const float* __restrict__ f2,
                                                 const float* __restrict__ gmax,
                                                 float* __restrict__ numb,
                                                 float* __restrict__ denb,
                                                 int kchunk, int nsplit) {
    __shared__ __align__(16) short ldsW[2][8192];   // 2 x [128 rows][64 cols]
    const int tid = threadIdx.x;
    const int lane = tid & 63;
    const int wave = tid >> 6;
    const int split = blockIdx.x & (nsplit - 1);
    const int rt = blockIdx.x / nsplit;
    const int rowbase = rt * 64 + wave * 16;
    const int col = lane & 15;
    const int kg = lane >> 4;
    const int arow = rowbase + col;

    const float f1r = f1[arow];
    const float gm = gmax[0];
    const float t0v = f1r + gm;
    const float mhat = fmaxf(t0v, LRELU_A * t0v);   // row-max upper bound
    const float mh2 = mhat * L2E;

    const int kbase0 = split * kchunk;
    const float* f2p = f2 + kbase0 + kg * 8;
    const int* adjp = adj + (size_t)arow * NN + kbase0 + kg * 8;

    // staging map: thread stages rows tq+{0,32,64,96}, j-slot ts; swizzled slot
    const int tq = tid >> 3;
    const int ts = tid & 7;
    const short* wsrc = WhT + (size_t)tq * NN + kbase0 + ts * 8;
    short* wdst0 = &ldsW[0][tq * 64 + ((ts ^ (tq & 7)) * 8)];
    short* wdst1 = &ldsW[1][tq * 64 + ((ts ^ (tq & 7)) * 8)];

    // compute-read bases (body0 / body1 within a 64-col tile)
    const short* lrdE0 = &ldsW[0][col * 64 + ((kg ^ (col & 7)) * 8)];
    const short* lrdE1 = &ldsW[0][col * 64 + (((kg ^ (col & 7)) * 8) ^ 32)];
    const short* lrdO0 = lrdE0 + 8192;
    const short* lrdO1 = lrdE1 + 8192;

    f32x4 acc[8] = {};
    float den = 0.0f;

    // prologue: stage tile 0 -> buf0; prefetch adj for steps 0 and 1
    {
        short8 r0 = *(const short8*)(wsrc);
        short8 r1 = *(const short8*)(wsrc + 32 * NN);
        short8 r2 = *(const short8*)(wsrc + 64 * NN);
        short8 r3 = *(const short8*)(wsrc + 96 * NN);
        *(short8*)(wdst0) = r0;
        *(short8*)(wdst0 + 2048) = r1;
        *(short8*)(wdst0 + 4096) = r2;
        *(short8*)(wdst0 + 6144) = r3;
    }
    i32x4 xa0 = *(const i32x4*)(adjp + 0);
    i32x4 xa1 = *(const i32x4*)(adjp + 4);
    i32x4 xa2 = *(const i32x4*)(adjp + 32);
    i32x4 xa3 = *(const i32x4*)(adjp + 36);
    i32x4 xb0 = *(const i32x4*)(adjp + 64);
    i32x4 xb1 = *(const i32x4*)(adjp + 68);
    i32x4 xb2 = *(const i32x4*)(adjp + 96);
    i32x4 xb3 = *(const i32x4*)(adjp + 100);
    asm volatile("s_waitcnt lgkmcnt(0)" ::: "memory");
    __builtin_amdgcn_s_barrier();

    for (int koff = 0; koff < kchunk; koff += 128) {
        GAT_STEP(koff,      xa0, xa1, xa2, xa3, lrdE0, lrdE1, wdst1);   // even: read buf0, write buf1
        GAT_STEP(koff + 64, xb0, xb1, xb2, xb3, lrdO0, lrdO1, wdst0);   // odd:  read buf1, write buf0
    }

    // reduce den across the 4 kg groups
    den += __shfl_xor(den, 16, 64);
    den += __shfl_xor(den, 32, 64);
    if (lane < 16) denb[(size_t)split * NN + rowbase + lane] = den;

    float* np = numb + ((size_t)split * NN + rowbase) * FOUT;
    const int rsub = (lane >> 4) * 4;
    #pragma unroll
    for (int t = 0; t < 8; ++t) {
        #pragma unroll
        for (int r = 0; r < 4; ++r) {
            np[(size_t)(rsub + r) * FOUT + t * 16 + col] = acc[t][r];
        }
    }
}

// K3: sum split partials, divide, ELU.
__global__ __launch_bounds__(256) void k_final(const float* __restrict__ numb,
                                               const float* __restrict__ denb,
                                               float* __restrict__ out,
                                               int splitk) {
    const int idx = blockIdx.x * 256 + threadIdx.x;
    const int row = idx >> 7;
    float s = 0.0f, d = 0.0f;
    for (int sp = 0; sp < splitk; ++sp) {
        s += numb[((size_t)sp * NN) * FOUT + idx];
        d += denb[(size_t)sp * NN + row];
    }
    float v = s / d;
    out[idx] = v > 0.0f ? v : expm1f(v);
}

extern "C" void kernel_launch(void* const* d_in, const int* in_sizes, int n_in,
                              void* d_out, int out_size, void* d_ws, size_t ws_size,
                              hipStream_t stream) {
    const float* h = (const float*)d_in[0];
    const int* adj = (const int*)d_in[1];
    const float* W = (const float*)d_in[2];
    const float* a = (const float*)d_in[3];
    float* out = (float*)d_out;

    char* ws = (char*)d_ws;
    size_t off = 0;
    auto alloc = [&](size_t nbytes) {
        char* p = ws + off;
        off = (off + nbytes + 255) & ~(size_t)255;
        return p;
    };
    float* Wh  = (float*)alloc((size_t)NN * FOUT * 4);
    short* WhT = (short*)alloc((size_t)FOUT * NN * 2);
    float* f1  = (float*)alloc(NN * 4);
    float* f2  = (float*)alloc(NN * 4);
    float* gmx = (float*)alloc(256);

    int splitk = 8;
    while (splitk > 1 &&
           off + (size_t)splitk * ((size_t)NN * FOUT * 4 + NN * 4 + 512) > ws_size)
        splitk >>= 1;
    float* numb = (float*)alloc((size_t)splitk * NN * FOUT * 4);
    float* denb = (float*)alloc((size_t)splitk * NN * 4);
    const int kchunk = NN / splitk;

    k_wh<<<NN / 8, 256, 0, stream>>>(h, W, a, Wh, f1, f2);
    k_transpose<<<(NN / 32) * (FOUT / 32), 256, 0, stream>>>(Wh, WhT);
    k_gmax<<<1, 256, 0, stream>>>(f2, gmx);
    k_attn<<<(NN / 64) * splitk, 256, 0, stream>>>(adj, WhT, f1, f2, gmx, numb, denb,
                                                   kchunk, splitk);
    k_final<<<NN * FOUT / 256, 256, 0, stream>>>(numb, denb, out, splitk);
}